// Round 1
// baseline (450.654 us; speedup 1.0000x reference)
//
#include <hip/hip_runtime.h>

#define N_TOK 8192
#define D_IN 384
#define D_H 64
#define NHEADS 4
#define N_CLS 6
#define LN_EPS 1e-5f

typedef __attribute__((ext_vector_type(8))) short short8;
typedef __attribute__((ext_vector_type(4))) float f32x4;

__device__ __forceinline__ unsigned short f2bf(float f) {
    unsigned int u = __float_as_uint(f);
    u += 0x7FFFu + ((u >> 16) & 1u);          // RNE (finite values only here)
    return (unsigned short)(u >> 16);
}
__device__ __forceinline__ float bf2f(unsigned short s) {
    return __uint_as_float(((unsigned int)s) << 16);
}

// ---------------------------------------------------------------------------
// Stage 1: h = relu(x @ proj_w + proj_b); hp[h] = h @ head_w[h] + head_b[h]
// Outputs: hp bf16 [H][N][64] row-major, Vf bf16 [H][N/8][64][8] (key-grouped
// for PV B-frags), ssq fp32 [H][N] computed from the bf16-rounded hp.
// Block = 256 thr = 4 waves, one row per wave (lane = d).
// ---------------------------------------------------------------------------
__global__ __launch_bounds__(256) void stage1_kernel(
    const float* __restrict__ x, const float* __restrict__ proj_w,
    const float* __restrict__ proj_b, const float* __restrict__ head_w,
    const float* __restrict__ head_b,
    unsigned short* __restrict__ hp, unsigned short* __restrict__ Vf,
    float* __restrict__ ssq)
{
    const int lane = threadIdx.x & 63;
    const int ty   = threadIdx.x >> 6;
    const int row  = blockIdx.x * 4 + ty;

    __shared__ float h_sh[4][64];

    float acc = proj_b[lane];
    const float4* xr = (const float4*)(x + row * D_IN);
    #pragma unroll 4
    for (int k4 = 0; k4 < D_IN / 4; ++k4) {
        float4 xv = xr[k4];
        int k = k4 * 4;
        acc = fmaf(xv.x, proj_w[(k + 0) * 64 + lane], acc);
        acc = fmaf(xv.y, proj_w[(k + 1) * 64 + lane], acc);
        acc = fmaf(xv.z, proj_w[(k + 2) * 64 + lane], acc);
        acc = fmaf(xv.w, proj_w[(k + 3) * 64 + lane], acc);
    }
    h_sh[ty][lane] = fmaxf(acc, 0.f);
    __syncthreads();

    #pragma unroll
    for (int hh = 0; hh < NHEADS; ++hh) {
        float a2 = head_b[hh * 64 + lane];
        const float* wb = head_w + hh * 64 * 64;
        #pragma unroll 4
        for (int e4 = 0; e4 < 16; ++e4) {
            float4 hv = *(const float4*)&h_sh[ty][e4 * 4];
            int e = e4 * 4;
            a2 = fmaf(hv.x, wb[(e + 0) * 64 + lane], a2);
            a2 = fmaf(hv.y, wb[(e + 1) * 64 + lane], a2);
            a2 = fmaf(hv.z, wb[(e + 2) * 64 + lane], a2);
            a2 = fmaf(hv.w, wb[(e + 3) * 64 + lane], a2);
        }
        unsigned short hb = f2bf(a2);
        float hf = bf2f(hb);
        hp[(hh * N_TOK + row) * 64 + lane] = hb;
        // Vf[h][row/8][d][row%8]
        Vf[((hh * (N_TOK / 8) + (row >> 3)) * 64 + lane) * 8 + (row & 7)] = hb;
        float s = hf * hf;
        #pragma unroll
        for (int off = 32; off > 0; off >>= 1) s += __shfl_xor(s, off);
        if (lane == 0) ssq[hh * N_TOK + row] = s;
    }
}

// ---------------------------------------------------------------------------
// Flash distance-attention. Grid (128 q-tiles, 4 heads, 2 k-splits) x 256 thr.
// Wave w owns query rows q0+16w..+15. Max logit is the constant 0 (diagonal),
// so no online rescaling: accumulate O = sum exp(-d) hp, l = sum exp(-d).
// MFMA 16x16x32 bf16; verified layouts:
//   A[m=lane&15][k=quad*8+j], B[k=quad*8+j][n=lane&15],
//   C/D: col=lane&15, row=quad*4+reg.
// ---------------------------------------------------------------------------
__global__ __launch_bounds__(256) void flash_kernel(
    const unsigned short* __restrict__ hp, const unsigned short* __restrict__ Vf,
    const float* __restrict__ ssq, float* __restrict__ Og, float* __restrict__ Lg)
{
    const int qt    = blockIdx.x;           // 0..127
    const int head  = blockIdx.y;           // 0..3
    const int split = blockIdx.z;           // 0..1
    const int q0    = qt * 64;
    const int w     = threadIdx.x >> 6;
    const int lane  = threadIdx.x & 63;
    const int col   = lane & 15;
    const int quad  = lane >> 4;

    // Per-wave P tile, 16 rows x 64 cols, padded to 88 (176 B row: 16B-aligned,
    // 2-way-max bank aliasing on b128 reads -> free).
    __shared__ __align__(16) unsigned short Psh[4][16][88];

    const unsigned short* hpH = hp + head * (N_TOK * 64);
    const unsigned short* VfH = Vf + head * (N_TOK * 64);
    const float* ssqH = ssq + head * N_TOK;

    short8 aQ[2];
    {
        const unsigned short* qrow = hpH + (q0 + w * 16 + col) * 64;
        aQ[0] = *(const short8*)(qrow + quad * 8);
        aQ[1] = *(const short8*)(qrow + 32 + quad * 8);
    }
    float ssqn[4];
    #pragma unroll
    for (int r = 0; r < 4; ++r)
        ssqn[r] = ssqH[q0 + w * 16 + quad * 4 + r];

    const f32x4 zero4 = {0.f, 0.f, 0.f, 0.f};
    f32x4 accO[4] = {zero4, zero4, zero4, zero4};
    f32x4 accL = zero4;
    const short8 ones = {16256,16256,16256,16256,16256,16256,16256,16256}; // bf16 1.0

    const int kt0 = split * 64;
    for (int kt = kt0; kt < kt0 + 64; ++kt) {
        // ---- S = Q.K^T (cross terms) ----
        f32x4 accS[4] = {zero4, zero4, zero4, zero4};
        const unsigned short* kbase = hpH + (kt * 64) * 64;
        #pragma unroll
        for (int nt = 0; nt < 4; ++nt) {
            const unsigned short* krow = kbase + (nt * 16 + col) * 64;
            short8 b0 = *(const short8*)(krow + quad * 8);
            short8 b1 = *(const short8*)(krow + 32 + quad * 8);
            accS[nt] = __builtin_amdgcn_mfma_f32_16x16x32_bf16(aQ[0], b0, accS[nt], 0, 0, 0);
            accS[nt] = __builtin_amdgcn_mfma_f32_16x16x32_bf16(aQ[1], b1, accS[nt], 0, 0, 0);
        }
        // ---- sq -> dist -> p, write P tile (bf16) to per-wave LDS ----
        const bool diagt = (kt == qt);
        #pragma unroll
        for (int nt = 0; nt < 4; ++nt) {
            float sm = ssqH[kt * 64 + nt * 16 + col];
            #pragma unroll
            for (int r = 0; r < 4; ++r) {
                float sq = fmaf(accS[nt][r], -2.f, ssqn[r] + sm);
                float dist = sqrtf(fmaxf(sq, 0.f));
                float p = __expf(-dist);
                if (diagt && (w * 16 + quad * 4 + r) == (nt * 16 + col)) p = 1.0f;
                Psh[w][quad * 4 + r][nt * 16 + col] = f2bf(p);
            }
        }
        // ---- PV: O += P.V, l += rowsum(P) (ones-MFMA). Wave-private LDS,
        //      in-order DS pipe -> no barrier needed. ----
        #pragma unroll
        for (int c = 0; c < 2; ++c) {
            short8 aP = *(const short8*)&Psh[w][col][c * 32 + quad * 8];
            accL = __builtin_amdgcn_mfma_f32_16x16x32_bf16(aP, ones, accL, 0, 0, 0);
            #pragma unroll
            for (int dt = 0; dt < 4; ++dt) {
                const unsigned short* vptr =
                    VfH + ((kt * 8 + c * 4 + quad) * 64 + dt * 16 + col) * 8;
                short8 bV = *(const short8*)vptr;
                accO[dt] = __builtin_amdgcn_mfma_f32_16x16x32_bf16(aP, bV, accO[dt], 0, 0, 0);
            }
        }
    }

    // ---- epilogue: write unnormalized O and l for this split ----
    float* og = Og + (size_t)(split * NHEADS + head) * N_TOK * 64;
    float* lg = Lg + (size_t)(split * NHEADS + head) * N_TOK;
    #pragma unroll
    for (int r = 0; r < 4; ++r) {
        int row = q0 + w * 16 + quad * 4 + r;
        #pragma unroll
        for (int dt = 0; dt < 4; ++dt)
            og[row * 64 + dt * 16 + col] = accO[dt][r];
        if (col == 0) lg[row] = accL[r];
    }
}

// ---------------------------------------------------------------------------
// Combine: merge splits, head-softmax mix, layernorm, FC. One wave per row.
// ---------------------------------------------------------------------------
__global__ __launch_bounds__(256) void combine_kernel(
    const float* __restrict__ Og, const float* __restrict__ Lg,
    const float* __restrict__ attn_w, const float* __restrict__ gamma,
    const float* __restrict__ beta, const float* __restrict__ fc_w,
    const float* __restrict__ fc_b, float* __restrict__ out)
{
    const int lane = threadIdx.x & 63;
    const int ty   = threadIdx.x >> 6;
    const int row  = blockIdx.x * 4 + ty;

    float a0 = attn_w[0], a1 = attn_w[1], a2 = attn_w[2], a3 = attn_w[3];
    float m = fmaxf(fmaxf(a0, a1), fmaxf(a2, a3));
    float e0 = __expf(a0 - m), e1 = __expf(a1 - m), e2 = __expf(a2 - m), e3 = __expf(a3 - m);
    float inv = 1.f / (e0 + e1 + e2 + e3);
    float aw[4] = {e0 * inv, e1 * inv, e2 * inv, e3 * inv};

    float c = 0.f;
    #pragma unroll
    for (int hh = 0; hh < NHEADS; ++hh) {
        float l = Lg[hh * N_TOK + row] + Lg[(NHEADS + hh) * N_TOK + row];
        float o = Og[(size_t)(hh * N_TOK + row) * 64 + lane]
                + Og[(size_t)((NHEADS + hh) * N_TOK + row) * 64 + lane];
        c += aw[hh] * o / l;
    }

    float s = c;
    #pragma unroll
    for (int off = 32; off > 0; off >>= 1) s += __shfl_xor(s, off);
    float mu = s * (1.f / 64.f);
    float d = c - mu;
    float v = d * d;
    #pragma unroll
    for (int off = 32; off > 0; off >>= 1) v += __shfl_xor(v, off);
    float normed = d * rsqrtf(v * (1.f / 64.f) + LN_EPS) * gamma[lane] + beta[lane];

    float lg[N_CLS];
    #pragma unroll
    for (int cc = 0; cc < N_CLS; ++cc) {
        float p = normed * fc_w[lane * N_CLS + cc];
        #pragma unroll
        for (int off = 32; off > 0; off >>= 1) p += __shfl_xor(p, off);
        lg[cc] = p;
    }
    if (lane == 0) {
        #pragma unroll
        for (int cc = 0; cc < N_CLS; ++cc)
            out[row * N_CLS + cc] = lg[cc] + fc_b[cc];
    }
}

// ---------------------------------------------------------------------------
extern "C" void kernel_launch(void* const* d_in, const int* in_sizes, int n_in,
                              void* d_out, int out_size, void* d_ws, size_t ws_size,
                              hipStream_t stream)
{
    const float* x      = (const float*)d_in[0];
    const float* proj_w = (const float*)d_in[1];
    const float* proj_b = (const float*)d_in[2];
    const float* head_w = (const float*)d_in[3];
    const float* head_b = (const float*)d_in[4];
    const float* attn_w = (const float*)d_in[5];
    const float* gamma  = (const float*)d_in[6];
    const float* beta   = (const float*)d_in[7];
    const float* fc_w   = (const float*)d_in[8];
    const float* fc_b   = (const float*)d_in[9];
    float* out = (float*)d_out;

    char* ws = (char*)d_ws;
    // ws layout (bytes):
    //   hp   bf16 [4][8192][64]        @ 0        (4 MB)
    //   Vf   bf16 [4][1024][64][8]     @ 4 MB     (4 MB)
    //   ssq  f32  [4][8192]            @ 8 MB     (128 KB)
    //   Og   f32  [2][4][8192][64]     @ 8M+128K  (16 MB)
    //   Lg   f32  [2][4][8192]         @ 24M+128K (256 KB)
    unsigned short* hp = (unsigned short*)(ws);
    unsigned short* Vf = (unsigned short*)(ws + (4u << 20));
    float* ssq = (float*)(ws + (8u << 20));
    float* Og  = (float*)(ws + (8u << 20) + (128u << 10));
    float* Lg  = (float*)(ws + (24u << 20) + (128u << 10));

    stage1_kernel<<<N_TOK / 4, 256, 0, stream>>>(x, proj_w, proj_b, head_w, head_b,
                                                 hp, Vf, ssq);
    dim3 g2(N_TOK / 64, NHEADS, 2);
    flash_kernel<<<g2, 256, 0, stream>>>(hp, Vf, ssq, Og, Lg);
    combine_kernel<<<N_TOK / 4, 256, 0, stream>>>(Og, Lg, attn_w, gamma, beta,
                                                  fc_w, fc_b, out);
}

// Round 2
// 425.378 us; speedup vs baseline: 1.0594x; 1.0594x over previous
//
#include <hip/hip_runtime.h>

#define N_TOK 8192
#define D_IN 384
#define D_H 64
#define NHEADS 4
#define N_CLS 6
#define LN_EPS 1e-5f

typedef __attribute__((ext_vector_type(8))) short short8;
typedef __attribute__((ext_vector_type(4))) float f32x4;

#define L2E2 2.08136898100560774f   /* (log2 e)^2 */

__device__ __forceinline__ unsigned short f2bf(float f) {
    unsigned int u = __float_as_uint(f);
    u += 0x7FFFu + ((u >> 16) & 1u);          // RNE (finite values only here)
    return (unsigned short)(u >> 16);
}
__device__ __forceinline__ float bf2f(unsigned short s) {
    return __uint_as_float(((unsigned int)s) << 16);
}

// Permuted key position within a 64-key tile (pairs bf16 cols for packed LDS
// writes). P-columns and V-rows use the same bijection -> PV invariant.
__device__ __forceinline__ int kperm(int k) {
    return (k & 32) + 2 * (k & 15) + ((k >> 4) & 1);
}

// ---------------------------------------------------------------------------
// Stage 1: h = relu(x @ proj_w + proj_b); hp[h] = h @ head_w[h] + head_b[h]
// 4 rows per wave (weight loads reused x4 in registers).
// Outputs: hp bf16 [H][N][64] row-major, Vf bf16 key-grouped+permuted for PV
// B-frags, ssq2 fp32 [H][N] = (sum hp^2) * (log2 e)^2  (pre-scaled).
// ---------------------------------------------------------------------------
__global__ __launch_bounds__(256) void stage1_kernel(
    const float* __restrict__ x, const float* __restrict__ proj_w,
    const float* __restrict__ proj_b, const float* __restrict__ head_w,
    const float* __restrict__ head_b,
    unsigned short* __restrict__ hp, unsigned short* __restrict__ Vf,
    float* __restrict__ ssq2)
{
    const int lane = threadIdx.x & 63;
    const int ty   = threadIdx.x >> 6;
    const int rb   = blockIdx.x * 16 + ty * 4;   // 4 rows per wave

    __shared__ float h_sh[4][64][4];             // [wave][feature][row]

    float acc[4];
    {
        float b = proj_b[lane];
        #pragma unroll
        for (int r = 0; r < 4; ++r) acc[r] = b;
    }
    const float* x0 = x + (size_t)rb * D_IN;
    #pragma unroll 2
    for (int k4 = 0; k4 < D_IN / 4; ++k4) {
        float w0 = proj_w[(k4 * 4 + 0) * 64 + lane];
        float w1 = proj_w[(k4 * 4 + 1) * 64 + lane];
        float w2 = proj_w[(k4 * 4 + 2) * 64 + lane];
        float w3 = proj_w[(k4 * 4 + 3) * 64 + lane];
        #pragma unroll
        for (int r = 0; r < 4; ++r) {
            float4 xv = *(const float4*)(x0 + r * D_IN + k4 * 4); // wave-uniform
            acc[r] = fmaf(xv.x, w0, acc[r]);
            acc[r] = fmaf(xv.y, w1, acc[r]);
            acc[r] = fmaf(xv.z, w2, acc[r]);
            acc[r] = fmaf(xv.w, w3, acc[r]);
        }
    }
    #pragma unroll
    for (int r = 0; r < 4; ++r) h_sh[ty][lane][r] = fmaxf(acc[r], 0.f);
    // wave-private LDS segment; in-order DS pipe -> no barrier needed

    #pragma unroll
    for (int hh = 0; hh < NHEADS; ++hh) {
        float a[4];
        {
            float b = head_b[hh * 64 + lane];
            #pragma unroll
            for (int r = 0; r < 4; ++r) a[r] = b;
        }
        const float* wb = head_w + hh * 64 * 64;
        #pragma unroll 4
        for (int e = 0; e < 64; ++e) {
            float wv = wb[e * 64 + lane];
            float4 hv = *(const float4*)&h_sh[ty][e][0];   // uniform -> broadcast
            a[0] = fmaf(hv.x, wv, a[0]);
            a[1] = fmaf(hv.y, wv, a[1]);
            a[2] = fmaf(hv.z, wv, a[2]);
            a[3] = fmaf(hv.w, wv, a[3]);
        }
        #pragma unroll
        for (int r = 0; r < 4; ++r) {
            int row = rb + r;
            unsigned short hb = f2bf(a[r]);
            float hf = bf2f(hb);
            hp[(hh * N_TOK + row) * 64 + lane] = hb;
            int p = kperm(row & 63);
            Vf[((hh * (N_TOK / 8) + ((row >> 6) << 3) + (p >> 3)) * 64 + lane) * 8
               + (p & 7)] = hb;
            float s = hf * hf;
            #pragma unroll
            for (int off = 32; off > 0; off >>= 1) s += __shfl_xor(s, off);
            if (lane == 0) ssq2[hh * N_TOK + row] = s * L2E2;
        }
    }
}

// ---------------------------------------------------------------------------
// Flash distance-attention. Grid (8 head/split combos = XCDs, 128 q-tiles).
// Wave w owns query rows q0+16w..+15. Max logit is 0 (diagonal) -> no online
// rescaling: O = sum exp(-d) hp, l = sum exp(-d) just accumulate.
// p = exp2(-sqrt(sq * (log2 e)^2)) with ssq pre-scaled; raw v_sqrt/v_exp.
// P packed to bf16 pairs via v_perm (truncation; diag forced to exact 1.0).
// MFMA 16x16x32 bf16; layouts: A[m=lane&15][k=quad*8+j],
// B[k=quad*8+j][n=lane&15], C/D: col=lane&15, row=quad*4+reg.
// ---------------------------------------------------------------------------
__global__ __launch_bounds__(256) void flash_kernel(
    const unsigned short* __restrict__ hp, const unsigned short* __restrict__ Vf,
    const float* __restrict__ ssq2, float* __restrict__ Og, float* __restrict__ Lg)
{
    const int head  = blockIdx.x >> 1;       // combo -> XCD: one head per XCD
    const int split = blockIdx.x & 1;
    const int qt    = blockIdx.y;            // 0..127
    const int q0    = qt * 64;
    const int w     = threadIdx.x >> 6;
    const int lane  = threadIdx.x & 63;
    const int col   = lane & 15;
    const int quad  = lane >> 4;

    // Per-wave P tile, 16 rows x 64 (permuted) cols, pitch 72 shorts (144 B:
    // 16B-aligned rows, <=2-way bank aliasing on the b32 writes -> free).
    __shared__ __align__(16) unsigned short Psh[4][16][72];

    const unsigned short* hpH = hp + head * (N_TOK * 64);
    const unsigned short* VfH = Vf + head * (N_TOK * 64);
    const float* ssqH = ssq2 + head * N_TOK;

    short8 aQ[2];
    {
        const unsigned short* qrow = hpH + (q0 + w * 16 + col) * 64;
        aQ[0] = *(const short8*)(qrow + quad * 8);
        aQ[1] = *(const short8*)(qrow + 32 + quad * 8);
    }
    float ssqn2[4];
    #pragma unroll
    for (int r = 0; r < 4; ++r)
        ssqn2[r] = ssqH[q0 + w * 16 + quad * 4 + r];

    const f32x4 zero4 = {0.f, 0.f, 0.f, 0.f};
    f32x4 accO[4] = {zero4, zero4, zero4, zero4};
    f32x4 accL = zero4;
    const short8 ones = {16256,16256,16256,16256,16256,16256,16256,16256}; // bf16 1.0
    const float NEG2L2 = -2.0f * L2E2;

    const int kt0 = split * 64;
    #pragma unroll 1
    for (int kt = kt0; kt < kt0 + 64; ++kt) {
        const unsigned short* kb = hpH + kt * 4096;
        const unsigned short* vb = VfH + kt * 4096;

        // key sum-squares (pre-scaled), prefetched
        float sm2[4];
        #pragma unroll
        for (int nt = 0; nt < 4; ++nt) sm2[nt] = ssqH[kt * 64 + nt * 16 + col];

        // V fragments (independent of S -> early issue)
        short8 bV[2][4];
        #pragma unroll
        for (int c = 0; c < 2; ++c)
            #pragma unroll
            for (int dt = 0; dt < 4; ++dt)
                bV[c][dt] = *(const short8*)(vb + ((c * 4 + quad) * 64 + dt * 16 + col) * 8);

        // ---- S = Q.K^T cross terms ----
        f32x4 accS[4] = {zero4, zero4, zero4, zero4};
        #pragma unroll
        for (int nt = 0; nt < 4; ++nt) {
            const unsigned short* kr = kb + (nt * 16 + col) * 64 + quad * 8;
            short8 b0 = *(const short8*)kr;
            short8 b1 = *(const short8*)(kr + 32);
            accS[nt] = __builtin_amdgcn_mfma_f32_16x16x32_bf16(aQ[0], b0, accS[nt], 0, 0, 0);
            accS[nt] = __builtin_amdgcn_mfma_f32_16x16x32_bf16(aQ[1], b1, accS[nt], 0, 0, 0);
        }

        // ---- p = exp2(-sqrt(max(sq',0))) : add, fma, max, sqrt, exp ----
        float pf[4][4];
        #pragma unroll
        for (int nt = 0; nt < 4; ++nt)
            #pragma unroll
            for (int r = 0; r < 4; ++r) {
                float sq = fmaf(accS[nt][r], NEG2L2, ssqn2[r] + sm2[nt]);
                float d2 = __builtin_amdgcn_sqrtf(fmaxf(sq, 0.f));
                pf[nt][r] = __builtin_amdgcn_exp2f(-d2);
            }

        // ---- pack bf16 pairs (v_perm truncation), 8 ds_write_b32 ----
        #pragma unroll
        for (int r = 0; r < 4; ++r) {
            unsigned int d0 = __builtin_amdgcn_perm(__float_as_uint(pf[1][r]),
                                                    __float_as_uint(pf[0][r]), 0x07060302u);
            unsigned int d1 = __builtin_amdgcn_perm(__float_as_uint(pf[3][r]),
                                                    __float_as_uint(pf[2][r]), 0x07060302u);
            int rr = quad * 4 + r;
            *(unsigned int*)&Psh[w][rr][2 * col]      = d0;
            *(unsigned int*)&Psh[w][rr][32 + 2 * col] = d1;
        }
        // diag tile: force p=1.0 exactly (one predicated b16 write, 1/64 tiles)
        if (kt == qt && lane < 16)
            Psh[w][lane][((w & 2) << 4) + 2 * lane + (w & 1)] = 0x3F80;

        // ---- PV: O += P.V, l += rowsum(P). Wave-private LDS, no barrier ----
        #pragma unroll
        for (int c = 0; c < 2; ++c) {
            short8 aP = *(const short8*)&Psh[w][col][c * 32 + quad * 8];
            accL = __builtin_amdgcn_mfma_f32_16x16x32_bf16(aP, ones, accL, 0, 0, 0);
            #pragma unroll
            for (int dt = 0; dt < 4; ++dt)
                accO[dt] = __builtin_amdgcn_mfma_f32_16x16x32_bf16(aP, bV[c][dt], accO[dt], 0, 0, 0);
        }
    }

    // ---- epilogue: unnormalized O and l for this split ----
    float* og = Og + (size_t)(split * NHEADS + head) * N_TOK * 64;
    float* lg = Lg + (size_t)(split * NHEADS + head) * N_TOK;
    #pragma unroll
    for (int r = 0; r < 4; ++r) {
        int row = q0 + w * 16 + quad * 4 + r;
        #pragma unroll
        for (int dt = 0; dt < 4; ++dt)
            og[row * 64 + dt * 16 + col] = accO[dt][r];
        if (col == 0) lg[row] = accL[r];
    }
}

// ---------------------------------------------------------------------------
// Combine: merge splits, head-softmax mix, layernorm, FC. One wave per row.
// ---------------------------------------------------------------------------
__global__ __launch_bounds__(256) void combine_kernel(
    const float* __restrict__ Og, const float* __restrict__ Lg,
    const float* __restrict__ attn_w, const float* __restrict__ gamma,
    const float* __restrict__ beta, const float* __restrict__ fc_w,
    const float* __restrict__ fc_b, float* __restrict__ out)
{
    const int lane = threadIdx.x & 63;
    const int ty   = threadIdx.x >> 6;
    const int row  = blockIdx.x * 4 + ty;

    float a0 = attn_w[0], a1 = attn_w[1], a2 = attn_w[2], a3 = attn_w[3];
    float m = fmaxf(fmaxf(a0, a1), fmaxf(a2, a3));
    float e0 = __expf(a0 - m), e1 = __expf(a1 - m), e2 = __expf(a2 - m), e3 = __expf(a3 - m);
    float inv = 1.f / (e0 + e1 + e2 + e3);
    float aw[4] = {e0 * inv, e1 * inv, e2 * inv, e3 * inv};

    float c = 0.f;
    #pragma unroll
    for (int hh = 0; hh < NHEADS; ++hh) {
        float l = Lg[hh * N_TOK + row] + Lg[(NHEADS + hh) * N_TOK + row];
        float o = Og[(size_t)(hh * N_TOK + row) * 64 + lane]
                + Og[(size_t)((NHEADS + hh) * N_TOK + row) * 64 + lane];
        c += aw[hh] * o * __builtin_amdgcn_rcpf(l);
    }

    float s = c;
    #pragma unroll
    for (int off = 32; off > 0; off >>= 1) s += __shfl_xor(s, off);
    float mu = s * (1.f / 64.f);
    float d = c - mu;
    float v = d * d;
    #pragma unroll
    for (int off = 32; off > 0; off >>= 1) v += __shfl_xor(v, off);
    float normed = d * rsqrtf(v * (1.f / 64.f) + LN_EPS) * gamma[lane] + beta[lane];

    float lg[N_CLS];
    #pragma unroll
    for (int cc = 0; cc < N_CLS; ++cc) {
        float p = normed * fc_w[lane * N_CLS + cc];
        #pragma unroll
        for (int off = 32; off > 0; off >>= 1) p += __shfl_xor(p, off);
        lg[cc] = p;
    }
    if (lane == 0) {
        #pragma unroll
        for (int cc = 0; cc < N_CLS; ++cc)
            out[row * N_CLS + cc] = lg[cc] + fc_b[cc];
    }
}

// ---------------------------------------------------------------------------
extern "C" void kernel_launch(void* const* d_in, const int* in_sizes, int n_in,
                              void* d_out, int out_size, void* d_ws, size_t ws_size,
                              hipStream_t stream)
{
    const float* x      = (const float*)d_in[0];
    const float* proj_w = (const float*)d_in[1];
    const float* proj_b = (const float*)d_in[2];
    const float* head_w = (const float*)d_in[3];
    const float* head_b = (const float*)d_in[4];
    const float* attn_w = (const float*)d_in[5];
    const float* gamma  = (const float*)d_in[6];
    const float* beta   = (const float*)d_in[7];
    const float* fc_w   = (const float*)d_in[8];
    const float* fc_b   = (const float*)d_in[9];
    float* out = (float*)d_out;

    char* ws = (char*)d_ws;
    // ws layout (bytes):
    //   hp   bf16 [4][8192][64]        @ 0        (4 MB)
    //   Vf   bf16 [4][1024][64][8]     @ 4 MB     (4 MB, key-permuted)
    //   ssq2 f32  [4][8192]            @ 8 MB     (128 KB)
    //   Og   f32  [2][4][8192][64]     @ 8M+128K  (16 MB)
    //   Lg   f32  [2][4][8192]         @ 24M+128K (256 KB)
    unsigned short* hp = (unsigned short*)(ws);
    unsigned short* Vf = (unsigned short*)(ws + (4u << 20));
    float* ssq2 = (float*)(ws + (8u << 20));
    float* Og   = (float*)(ws + (8u << 20) + (128u << 10));
    float* Lg   = (float*)(ws + (24u << 20) + (128u << 10));

    stage1_kernel<<<N_TOK / 16, 256, 0, stream>>>(x, proj_w, proj_b, head_w, head_b,
                                                  hp, Vf, ssq2);
    dim3 g2(NHEADS * 2, N_TOK / 64);   // (head,split) fastest -> one head per XCD
    flash_kernel<<<g2, 256, 0, stream>>>(hp, Vf, ssq2, Og, Lg);
    combine_kernel<<<N_TOK / 4, 256, 0, stream>>>(Og, Lg, attn_w, gamma, beta,
                                                  fc_w, fc_b, out);
}